// Round 2
// baseline (560.819 us; speedup 1.0000x reference)
//
#include <hip/hip_runtime.h>
#include <hip/hip_bf16.h>

typedef unsigned short u16;
typedef unsigned int u32;
typedef __attribute__((ext_vector_type(8))) short bfrag;   // 8 bf16 in 4 VGPRs
typedef __attribute__((ext_vector_type(4))) float facc;    // 4 fp32 acc

#define B_  8
#define T_  2048
#define D_  1024
#define M_  16384      // B*T
#define NC_ 32         // scan chunks
#define L_  64         // chunk length

// ---------------- workspace layout (bytes), total ~206 MB ----------------
// y_local and res live in d_out (64 MB, dead until the final LN pass).
static constexpr size_t OFF_XHI   = 0;           // 32 MB bf16 hi(x)
static constexpr size_t OFF_XLO   = 33554432;    // 32 MB bf16 lo(x)
static constexpr size_t OFF_WIHI  = 67108864;    //  4 MB
static constexpr size_t OFF_WILO  = 71303168;    //  4 MB
static constexpr size_t OFF_WOHI  = 75497472;    //  2 MB
static constexpr size_t OFF_WOLO  = 77594624;    //  2 MB
static constexpr size_t OFF_ATANH = 79691776;    //  4 KB
static constexpr size_t OFF_G     = 79695872;    // 64 MB g; reused as y_hi/y_lo bf16
static constexpr size_t OFF_VAL   = 146804736;   // 64 MB val
static constexpr size_t OFF_CARRY = 213913600;   //  1 MB
static constexpr size_t OFF_CIN   = 214962176;   //  1 MB
// end = 216,010,752 bytes

// ---------------- helpers ----------------
__device__ __forceinline__ u16 f2bf(float f) {
  u32 u = __float_as_uint(f);
  u = (u + 0x7FFFu + ((u >> 16) & 1u)) >> 16;   // RNE
  return (u16)u;
}
__device__ __forceinline__ float bf2f(u16 h) { return __uint_as_float(((u32)h) << 16); }

__device__ __forceinline__ void gload16(const void* g, void* l) {
  __builtin_amdgcn_global_load_lds((const __attribute__((address_space(1))) u32*)g,
                                   (__attribute__((address_space(3))) u32*)l, 16, 0, 0);
}

// ---------------- kernel A: split f32 -> bf16 hi/lo ----------------
__global__ void split_kernel(const float* __restrict__ in, u16* __restrict__ hi,
                             u16* __restrict__ lo, int n4) {
  int i = blockIdx.x * 256 + threadIdx.x;
  if (i >= n4) return;
  float4 v = ((const float4*)in)[i];
  ushort4 h, l;
  h.x = f2bf(v.x); l.x = f2bf(v.x - bf2f(h.x));
  h.y = f2bf(v.y); l.y = f2bf(v.y - bf2f(h.y));
  h.z = f2bf(v.z); l.z = f2bf(v.z - bf2f(h.z));
  h.w = f2bf(v.w); l.w = f2bf(v.w - bf2f(h.w));
  ((ushort4*)hi)[i] = h;
  ((ushort4*)lo)[i] = l;
}

__global__ void tanh_kernel(const float* __restrict__ a_param, float* __restrict__ at) {
  int d = blockIdx.x * 256 + threadIdx.x;
  if (d < D_) at[d] = tanhf(a_param[d]);
}

// ---------------- GEMM: C[m,n] = sum_k A[m,k]*Bt[n,k]  (bf16x3 split) ----------------
// MODE 0: n<D -> out0 = sigmoid(c) (gate); n>=D -> out1 = c (val).  N=2048
// MODE 1: out0[m,n] = c + resx[m,n]                                  N=1024
template <int MODE>
__global__ __launch_bounds__(256, 2) void gemm_bf16x3(
    const u16* __restrict__ Ahi, const u16* __restrict__ Alo,
    const u16* __restrict__ Bhi, const u16* __restrict__ Blo,
    float* __restrict__ out0, float* __restrict__ out1, const float* __restrict__ resx) {
  // LDS tile: [128 rows][64 bf16] = hi k0..31 | lo k0..31, 16B-unit XOR swizzle by (row&7)
  __shared__ __attribute__((aligned(16))) u16 ldsA[128 * 64];
  __shared__ __attribute__((aligned(16))) u16 ldsB[128 * 64];
  const int tid = threadIdx.x;
  const int lane = tid & 63;
  const int wid = tid >> 6;
  const int wrow = wid >> 1, wcol = wid & 1;
  const int row0 = blockIdx.y * 128;   // M
  const int col0 = blockIdx.x * 128;   // N
  const int g = lane >> 4, lr = lane & 15;

  int aoh[4], aol[4], boh[4], bol[4];   // ushort offsets into LDS (constant over k-loop)
#pragma unroll
  for (int i = 0; i < 4; i++) {
    int ra = wrow * 64 + i * 16 + lr;
    aoh[i] = ra * 64 + ((g) ^ (ra & 7)) * 8;
    aol[i] = ra * 64 + ((4 + g) ^ (ra & 7)) * 8;
    int rb = wcol * 64 + i * 16 + lr;
    boh[i] = rb * 64 + ((g) ^ (rb & 7)) * 8;
    bol[i] = rb * 64 + ((4 + g) ^ (rb & 7)) * 8;
  }

  facc acc[4][4] = {};

  for (int kt = 0; kt < 1024 / 32; ++kt) {
    __syncthreads();
#pragma unroll
    for (int p = 0; p < 4; p++) {
      int idx = p * 256 + tid;          // linear 16B-unit index in tile
      int row = idx >> 3, u = idx & 7;
      int ulog = u ^ (row & 7);         // logical unit: 0-3 = hi k-groups, 4-7 = lo
      const u16* sa = ((ulog < 4) ? Ahi : Alo) + (size_t)(row0 + row) * 1024 + kt * 32 + (ulog & 3) * 8;
      gload16(sa, &ldsA[idx * 8]);
      const u16* sb = ((ulog < 4) ? Bhi : Blo) + (size_t)(col0 + row) * 1024 + kt * 32 + (ulog & 3) * 8;
      gload16(sb, &ldsB[idx * 8]);
    }
    __syncthreads();

    bfrag ah[4], al[4], bh[4], bl[4];
#pragma unroll
    for (int i = 0; i < 4; i++) {
      ah[i] = *(const bfrag*)&ldsA[aoh[i]];
      al[i] = *(const bfrag*)&ldsA[aol[i]];
      bh[i] = *(const bfrag*)&ldsB[boh[i]];
      bl[i] = *(const bfrag*)&ldsB[bol[i]];
    }
#pragma unroll
    for (int i = 0; i < 4; i++)
#pragma unroll
      for (int j = 0; j < 4; j++) {
        acc[i][j] = __builtin_amdgcn_mfma_f32_16x16x32_bf16(ah[i], bh[j], acc[i][j], 0, 0, 0);
        acc[i][j] = __builtin_amdgcn_mfma_f32_16x16x32_bf16(ah[i], bl[j], acc[i][j], 0, 0, 0);
        acc[i][j] = __builtin_amdgcn_mfma_f32_16x16x32_bf16(al[i], bh[j], acc[i][j], 0, 0, 0);
      }
  }

#pragma unroll
  for (int i = 0; i < 4; i++)
#pragma unroll
    for (int j = 0; j < 4; j++)
#pragma unroll
      for (int r = 0; r < 4; r++) {
        int m = row0 + wrow * 64 + i * 16 + g * 4 + r;   // verified C/D map
        int n = col0 + wcol * 64 + j * 16 + lr;
        float c = acc[i][j][r];
        if (MODE == 0) {
          if (n < D_) out0[(size_t)m * D_ + n] = 1.f / (1.f + expf(-c));
          else        out1[(size_t)m * D_ + (n - D_)] = c;
        } else {
          out0[(size_t)m * D_ + n] = c + resx[(size_t)m * D_ + n];
        }
      }
}

// ---------------- kernel C: depthwise conv(K=5,same) + gate + local scan ----------------
__global__ void convscan_kernel(const float* __restrict__ val, const float* __restrict__ gbuf,
                                const float* __restrict__ conv_w, const float* __restrict__ conv_b,
                                const float* __restrict__ at, float* __restrict__ y,
                                float* __restrict__ carry) {
  const int d = blockIdx.x * 256 + threadIdx.x;
  const int c = blockIdx.y;
  const int b = blockIdx.z;
  const int t0 = c * L_;
  float cw0 = conv_w[(size_t)d * 5 + 0], cw1 = conv_w[(size_t)d * 5 + 1],
        cw2 = conv_w[(size_t)d * 5 + 2], cw3 = conv_w[(size_t)d * 5 + 3],
        cw4 = conv_w[(size_t)d * 5 + 4];
  float cb = conv_b[d];
  float a = at[d];
  const size_t base = (size_t)b * T_ * D_ + d;
  // rolling window w0..w3 = val[t0-2 .. t0+1]
  float w0 = (t0 - 2 >= 0) ? val[base + (size_t)(t0 - 2) * D_] : 0.f;
  float w1 = (t0 - 1 >= 0) ? val[base + (size_t)(t0 - 1) * D_] : 0.f;
  float w2 = val[base + (size_t)t0 * D_];
  float w3 = val[base + (size_t)(t0 + 1) * D_];
  float h = 0.f;
  for (int tt = 0; tt < L_; ++tt) {
    int t = t0 + tt;
    float w4 = (t + 2 < T_) ? val[base + (size_t)(t + 2) * D_] : 0.f;
    float conv = fmaf(w0, cw0, fmaf(w1, cw1, fmaf(w2, cw2, fmaf(w3, cw3, fmaf(w4, cw4, cb)))));
    float gg = gbuf[base + (size_t)t * D_];
    h = fmaf(a, h, gg * conv);
    y[base + (size_t)t * D_] = h;
    w0 = w1; w1 = w2; w2 = w3; w3 = w4;
  }
  carry[((size_t)b * NC_ + c) * D_ + d] = h;
}

// ---------------- kernel D2: combine chunk carries -> carry-in per chunk ----------------
__global__ void carryfix_kernel(const float* __restrict__ carry, const float* __restrict__ at,
                                float* __restrict__ cin) {
  int idx = blockIdx.x * 256 + threadIdx.x;   // 8192 = B*D
  int b = idx >> 10, d = idx & 1023;
  float a = at[d];
  float p = a;
  p = p * p; p = p * p; p = p * p; p = p * p; p = p * p; p = p * p;   // a^64
  float H = 0.f;
  for (int c = 0; c < NC_; ++c) {
    size_t o = ((size_t)b * NC_ + c) * D_ + d;
    cin[o] = H;
    H = fmaf(p, H, carry[o]);
  }
}

// ---------------- kernel E: y = y_local + a^(tt+1)*Cin, split to bf16 hi/lo ----------------
__global__ void yfix_kernel(const float* __restrict__ yl, const float* __restrict__ cin,
                            const float* __restrict__ at, u16* __restrict__ yhi,
                            u16* __restrict__ ylo) {
  int i4 = blockIdx.x * 256 + threadIdx.x;    // 4,194,304 float4s
  int d4 = i4 & 255;
  int row = i4 >> 8;          // b*T + t
  int t = row & (T_ - 1);
  int b = row >> 11;
  int tt = t & (L_ - 1);
  int c = t >> 6;
  float4 y4 = ((const float4*)yl)[i4];
  float4 ci = ((const float4*)cin)[((size_t)b * NC_ + c) * 256 + d4];
  float4 av = ((const float4*)at)[d4];
  float e = (float)(tt + 1);
  float out[4];
  float ys[4] = {y4.x, y4.y, y4.z, y4.w};
  float cs[4] = {ci.x, ci.y, ci.z, ci.w};
  float as[4] = {av.x, av.y, av.z, av.w};
#pragma unroll
  for (int q = 0; q < 4; q++) {
    float a = as[q];
    float p = exp2f(log2f(fabsf(a)) * e);
    if (a < 0.f && ((tt + 1) & 1)) p = -p;
    out[q] = fmaf(p, cs[q], ys[q]);
  }
  ushort4 h, l;
  h.x = f2bf(out[0]); l.x = f2bf(out[0] - bf2f(h.x));
  h.y = f2bf(out[1]); l.y = f2bf(out[1] - bf2f(h.y));
  h.z = f2bf(out[2]); l.z = f2bf(out[2] - bf2f(h.z));
  h.w = f2bf(out[3]); l.w = f2bf(out[3] - bf2f(h.w));
  ((ushort4*)yhi)[i4] = h;
  ((ushort4*)ylo)[i4] = l;
}

// ---------------- kernel G: LayerNorm over D (safe in-place: res may == out) ----------------
__global__ void ln_kernel(const float* __restrict__ res, const float* __restrict__ lnw,
                          const float* __restrict__ lnb, float* __restrict__ out) {
  const int row = blockIdx.x;
  const int tid = threadIdx.x;
  float4 v = ((const float4*)res)[(size_t)row * 256 + tid];
  float s = v.x + v.y + v.z + v.w;
  float q = v.x * v.x + v.y * v.y + v.z * v.z + v.w * v.w;
#pragma unroll
  for (int m = 1; m < 64; m <<= 1) {
    s += __shfl_xor(s, m);
    q += __shfl_xor(q, m);
  }
  __shared__ float red[2][4];
  const int wid = tid >> 6, lane = tid & 63;
  if (lane == 0) { red[0][wid] = s; red[1][wid] = q; }
  __syncthreads();
  s = red[0][0] + red[0][1] + red[0][2] + red[0][3];
  q = red[1][0] + red[1][1] + red[1][2] + red[1][3];
  float mu = s * (1.f / D_);
  float var = fmaxf(q * (1.f / D_) - mu * mu, 0.f);
  float inv = rsqrtf(var + 1e-5f);
  float4 w = ((const float4*)lnw)[tid];
  float4 bb = ((const float4*)lnb)[tid];
  float4 o;
  o.x = (v.x - mu) * inv * w.x + bb.x;
  o.y = (v.y - mu) * inv * w.y + bb.y;
  o.z = (v.z - mu) * inv * w.z + bb.z;
  o.w = (v.w - mu) * inv * w.w + bb.w;
  ((float4*)out)[(size_t)row * 256 + tid] = o;
}

// ---------------- launch ----------------
extern "C" void kernel_launch(void* const* d_in, const int* in_sizes, int n_in,
                              void* d_out, int out_size, void* d_ws, size_t ws_size,
                              hipStream_t stream) {
  const float* x       = (const float*)d_in[0];
  const float* W_in    = (const float*)d_in[1];
  const float* conv_w  = (const float*)d_in[2];
  const float* conv_b  = (const float*)d_in[3];
  const float* a_param = (const float*)d_in[4];
  const float* W_out   = (const float*)d_in[5];
  const float* ln_w    = (const float*)d_in[6];
  const float* ln_b    = (const float*)d_in[7];
  float* out = (float*)d_out;
  char* ws = (char*)d_ws;

  u16* xhi  = (u16*)(ws + OFF_XHI);
  u16* xlo  = (u16*)(ws + OFF_XLO);
  u16* wihi = (u16*)(ws + OFF_WIHI);
  u16* wilo = (u16*)(ws + OFF_WILO);
  u16* wohi = (u16*)(ws + OFF_WOHI);
  u16* wolo = (u16*)(ws + OFF_WOLO);
  float* at    = (float*)(ws + OFF_ATANH);
  float* gbuf  = (float*)(ws + OFF_G);
  float* valb  = (float*)(ws + OFF_VAL);
  float* carry = (float*)(ws + OFF_CARRY);
  float* cin   = (float*)(ws + OFF_CIN);
  // d_out doubles as scratch: y_local before GEMM2, res after GEMM2 (LN is in-place-safe).
  float* ybuf = out;
  float* resb = out;
  u16* yhi = (u16*)(ws + OFF_G);              // reuse g region after conv/scan
  u16* ylo = (u16*)(ws + OFF_G + 33554432);

  split_kernel<<<16384, 256, 0, stream>>>(x, xhi, xlo, 4194304);
  split_kernel<<<2048, 256, 0, stream>>>(W_in, wihi, wilo, 524288);
  split_kernel<<<1024, 256, 0, stream>>>(W_out, wohi, wolo, 262144);
  tanh_kernel<<<4, 256, 0, stream>>>(a_param, at);

  gemm_bf16x3<0><<<dim3(16, 128), 256, 0, stream>>>(xhi, xlo, wihi, wilo, gbuf, valb, nullptr);

  convscan_kernel<<<dim3(4, 32, 8), 256, 0, stream>>>(valb, gbuf, conv_w, conv_b, at, ybuf, carry);
  carryfix_kernel<<<32, 256, 0, stream>>>(carry, at, cin);
  yfix_kernel<<<16384, 256, 0, stream>>>(ybuf, cin, at, yhi, ylo);

  gemm_bf16x3<1><<<dim3(8, 128), 256, 0, stream>>>(yhi, ylo, wohi, wolo, resb, nullptr, x);

  ln_kernel<<<16384, 256, 0, stream>>>(resb, ln_w, ln_b, out);
}